// Round 14
// baseline (199.641 us; speedup 1.0000x reference)
//
#include <hip/hip_runtime.h>

#define D_MODEL 1024
#define NUM_HEADS 16
#define SEQ 2048
#define BATCH 2

typedef __attribute__((ext_vector_type(8))) short bf16x8;
typedef __attribute__((ext_vector_type(4))) float f32x4;

__device__ __forceinline__ float bf2f(unsigned short u) {
    return __uint_as_float(((unsigned int)u) << 16);
}
__device__ __forceinline__ unsigned short f2bf(float f) {
    unsigned int u = __float_as_uint(f);
    return (unsigned short)((u + 0x7FFFu + ((u >> 16) & 1u)) >> 16);   // RTNE
}
__device__ __forceinline__ ushort4 pack4(float4 v) {
    return make_ushort4(f2bf(v.x), f2bf(v.y), f2bf(v.z), f2bf(v.w));
}

// async global->LDS, 16B per lane. LDS dest = wave-uniform base + lane*16.
__device__ __forceinline__ void gload_lds16(const unsigned short* g, unsigned short* l) {
    __builtin_amdgcn_global_load_lds(
        (const __attribute__((address_space(1))) unsigned int*)g,
        (__attribute__((address_space(3))) unsigned int*)l,
        16, 0, 0);
}

// Swizzled 16B read from a [N][64] bf16 LDS tile (128B rows, 8 chunks).
__device__ __forceinline__ bf16x8 lds_read_swz(const unsigned short (*tile)[64], int row, int chunk) {
    const char* p = reinterpret_cast<const char*>(tile);
    return *reinterpret_cast<const bf16x8*>(p + row * 128 + (((chunk ^ (row & 7))) << 4));
}

// 64B rows (BK=32 tiles, 4 chunks). XOR (row>>1)&3 (R10 fix: row&3 gave
// 4-way conflicts; (parity,slot) must cover all 8 combos across 16 rows).
__device__ __forceinline__ bf16x8 lds_read_swz32(const unsigned short (*tile)[32], int row, int chunk) {
    const char* p = reinterpret_cast<const char*>(tile);
    return *reinterpret_cast<const bf16x8*>(p + row * 64 + (((chunk ^ ((row >> 1) & 3))) << 4));
}

// Same pattern for 256B rows (128-wide bf16 tiles, 16 chunks, XOR row&15).
__device__ __forceinline__ bf16x8 lds_read_swz128(const unsigned short (*tile)[128], int row, int chunk) {
    const char* p = reinterpret_cast<const char*>(tile);
    return *reinterpret_cast<const bf16x8*>(p + row * 256 + (((chunk ^ (row & 15))) << 4));
}

// fp32 -> bf16 bulk convert (one float4 -> ushort4 per thread).
__global__ __launch_bounds__(256) void conv_kernel(
    const float* __restrict__ src, unsigned short* __restrict__ dst, int n4)
{
    int i = blockIdx.x * 256 + threadIdx.x;
    if (i < n4) {
        float4 v = reinterpret_cast<const float4*>(src)[i];
        reinterpret_cast<ushort4*>(dst)[i] = pack4(v);
    }
}

// Fused conversion of x + Wq/Wk/Wv + RoPE cos/sin table build.
__global__ __launch_bounds__(256) void conv4_kernel(
    const float* __restrict__ x, const float* __restrict__ Wq,
    const float* __restrict__ Wk, const float* __restrict__ Wv,
    unsigned short* __restrict__ xb, unsigned short* __restrict__ w3bf,
    float2* __restrict__ tab)
{
    int i = blockIdx.x * 256 + threadIdx.x;
    if (i < 1835008) {
        const float* src;
        unsigned short* dst;
        int off;
        if (i < 1048576) {
            src = x; dst = xb; off = i;
        } else {
            int j = i - 1048576;
            int which = j >> 18;            // 262144 = 2^18
            off = j & 0x3FFFF;
            src = (which == 0) ? Wq : (which == 1) ? Wk : Wv;
            dst = w3bf + ((size_t)which << 20);
        }
        float4 v = reinterpret_cast<const float4*>(src)[off];
        reinterpret_cast<ushort4*>(dst)[off] = pack4(v);
    } else {
        int idx = i - 1835008;              // 65536 entries
        int s = idx >> 5, d2 = idx & 31;
        float inv = powf(10000.0f, -(float)d2 / 32.0f);
        float sn, cs;
        sincosf((float)s * inv, &sn, &cs);
        tab[idx] = make_float2(cs, sn);
    }
}

// MFMA NT-GEMM: C[m,n] = sum_i xb[m,i] * W[n,i], all bf16.
// 128x128 tile, BK=32. T4 counted-vmcnt pipeline: 3 LDS buffers (48KB,
// still 3 blocks/CU since grid=768), depth-2 prefetch. Loop top waits
// vmcnt(4) (own 4 oldest loads = buffer i retired; i+1 stays in flight)
// + raw s_barrier -> collectively buffer i complete, never draining to 0.
// stage(i+2) issued after the barrier (its buffer's last reads completed
// before this barrier). Loads get 2 iterations of latency cover.
__global__ __launch_bounds__(256) void qkv_mfma_kernel(
    const unsigned short* __restrict__ xb,
    const unsigned short* __restrict__ w3,
    const float2* __restrict__ tab,
    unsigned short* __restrict__ qb, unsigned short* __restrict__ kb,
    unsigned short* __restrict__ vt)
{
    const int lin = blockIdx.x;
    const int b = lin & 7;
    const int t = lin >> 3;
    const int which = t % 3;
    const int y = t / 3;
    const unsigned short* __restrict__ W = w3 + (size_t)which * 1048576;
    const int m0 = y * 128;
    const int n0g = b * 128;

    __shared__ __align__(16) unsigned short As[3][128][32];   // 24 KB
    __shared__ __align__(16) unsigned short Bs[3][128][32];   // 24 KB

    const int tid = threadIdx.x;
    const int w = tid >> 6;
    const int lane = tid & 63;
    const int quad = lane >> 4;
    const int c15 = lane & 15;
    const int qm = w >> 1, qn = w & 1;
    const int srow4 = lane >> 2;
    const int sch4 = lane & 3;

    // 4 gload_lds per wave per stage (2 x A, 2 x B).
    auto stage = [&](int k0, int buf) {
#pragma unroll
        for (int i = 0; i < 2; i++) {
            const int row = i * 64 + w * 16 + srow4;
            const int ch = sch4 ^ ((row >> 1) & 3);
            gload_lds16(xb + (size_t)(m0 + row) * 1024 + k0 + ch * 8,
                        &As[buf][i * 64 + w * 16][0]);
            gload_lds16(W + (size_t)(n0g + row) * 1024 + k0 + ch * 8,
                        &Bs[buf][i * 64 + w * 16][0]);
        }
    };

    f32x4 acc[4][4];
#pragma unroll
    for (int mi = 0; mi < 4; mi++)
#pragma unroll
        for (int ni = 0; ni < 4; ni++) acc[mi][ni] = (f32x4){0.f, 0.f, 0.f, 0.f};

    stage(0, 0);
    stage(32, 1);
    for (int it = 0; it < 32; it++) {
        // buffer `it` complete after this wait+barrier; i+1 stays in flight
        if (it < 31) {
            asm volatile("s_waitcnt vmcnt(4)" ::: "memory");
        } else {
            asm volatile("s_waitcnt vmcnt(0)" ::: "memory");
        }
        __builtin_amdgcn_s_barrier();
        if (it + 2 < 32) stage((it + 2) * 32, (it + 2) % 3);

        const int cb = it % 3;
        bf16x8 af[4], bfr[4];
#pragma unroll
        for (int mi = 0; mi < 4; mi++)
            af[mi] = lds_read_swz32(As[cb], qm * 64 + mi * 16 + c15, quad);
#pragma unroll
        for (int ni = 0; ni < 4; ni++)
            bfr[ni] = lds_read_swz32(Bs[cb], qn * 64 + ni * 16 + c15, quad);
#pragma unroll
        for (int mi = 0; mi < 4; mi++)
#pragma unroll
            for (int ni = 0; ni < 4; ni++)
                acc[mi][ni] = __builtin_amdgcn_mfma_f32_16x16x32_bf16(af[mi], bfr[ni], acc[mi][ni], 0, 0, 0);
    }

    __syncthreads();
    unsigned short* stg = &As[0][0][0] + w * (16 * 72);
    const int hq = b * 2 + qn;
    unsigned short* outp = (which == 0) ? qb : kb;
    const int odd = c15 & 1;

#pragma unroll
    for (int mi = 0; mi < 4; mi++) {
#pragma unroll
        for (int r = 0; r < 4; r++) {
            int m = m0 + qm * 64 + mi * 16 + quad * 4 + r;
            int s = m & (SEQ - 1);
            const float2* trow = tab + (s << 5);
#pragma unroll
            for (int ni = 0; ni < 4; ni++) {
                float val = acc[mi][ni][r];
                float res;
                if (which < 2) {
                    float part = __shfl_xor(val, 1);
                    float2 cs = trow[(ni * 16 + c15) >> 1];
                    res = odd ? (part * cs.y + val * cs.x) : (val * cs.x - part * cs.y);
                } else {
                    res = val;
                }
                stg[(quad * 4 + r) * 72 + ni * 16 + c15] = f2bf(res);
            }
        }
        if (which < 2) {
            int row = lane >> 2;
            int ch = lane & 3;
            int m = m0 + qm * 64 + mi * 16 + row;
            int s = m & (SEQ - 1);
            int bb = m >> 11;
            size_t ob = (((size_t)bb * NUM_HEADS + hq) * SEQ + s) * 64 + ch * 16;
            uint4 v0 = *reinterpret_cast<const uint4*>(&stg[row * 72 + ch * 16]);
            uint4 v1 = *reinterpret_cast<const uint4*>(&stg[row * 72 + ch * 16 + 8]);
            *reinterpret_cast<uint4*>(&outp[ob]) = v0;
            *reinterpret_cast<uint4*>(&outp[ob + 8]) = v1;
        } else {
            int mbase = m0 + qm * 64 + mi * 16;
            int bb = mbase >> 11;
            int s_base = mbase & (SEQ - 1);
            unsigned short tmp[16];
#pragma unroll
            for (int sl = 0; sl < 16; sl++) tmp[sl] = stg[sl * 72 + lane];
            size_t ob = (((size_t)bb * NUM_HEADS + hq) * 64 + lane) * SEQ + s_base;
            *reinterpret_cast<uint4*>(&vt[ob])     = *reinterpret_cast<uint4*>(&tmp[0]);
            *reinterpret_cast<uint4*>(&vt[ob + 8]) = *reinterpret_cast<uint4*>(&tmp[8]);
        }
    }
}

// MFMA flash attention, 8-wave blocks with j-split wave groups.
// Grid is (bh, xpair) so the 16 blocks sharing one bh's K/V panel land on
// one XCD (lin == bh mod 8) -> panel re-reads are L2 hits (T1).
__global__ __launch_bounds__(512, 4) void attn_kernel(
    const unsigned short* __restrict__ qb, const unsigned short* __restrict__ kb,
    const unsigned short* __restrict__ vt, unsigned short* __restrict__ ab)
{
    const int xpair = blockIdx.y;   // 0..15
    const int bh = blockIdx.x;      // 0..31 (fast dim -> XCD clustering)
    const int b = bh >> 4, h = bh & 15;
    const size_t base = (size_t)bh * SEQ * 64;     // qb/kb [b][h][s][d]
    const size_t vbase = (size_t)bh * 64 * SEQ;    // vt [b][h][d][s]
    const int tid = threadIdx.x;
    const int w = tid >> 6;        // 0..7
    const int grp = w >> 2;        // 0 = A (low half), 1 = B (high half)
    const int wa = w & 3;          // wave-in-group; q-rows wa*16..+16
    const int lane = tid & 63;
    const int quad = lane >> 4;
    const int c15 = lane & 15;
    const int srow8 = lane >> 3;
    const int sch = lane & 7;
    const int srow16 = lane >> 4;
    const int sch16 = lane & 15;
    const float C = 0.125f;

    __shared__ __align__(16) unsigned short Ks[2][128][64];   // [buf][j][d], 32 KB
    __shared__ __align__(16) unsigned short Vs[2][64][128];   // [buf][d][j], 32 KB
    float* exch = (float*)&Ks[0][0][0];                 // B's O partial [64 q][65]
    float2* ml  = (float2*)((char*)&Ks[0][0][0] + 17152); // B's (m,l) per q
    unsigned short* ost = &Vs[0][0][0];                 // A store staging [64][72]

    auto stage = [&](int sj, int buf) {
        const int j0s = sj * 128;
#pragma unroll
        for (int i = 0; i < 2; i++) {
            const int krow = w * 16 + i * 8 + srow8;
            const int kch = sch ^ (krow & 7);
            gload_lds16(kb + base + (size_t)(j0s + krow) * 64 + kch * 8,
                        &Ks[buf][w * 16 + i * 8][0]);
            const int vrow = w * 8 + i * 4 + srow16;
            const int vch = sch16 ^ (vrow & 15);
            gload_lds16(vt + vbase + (size_t)vrow * SEQ + j0s + vch * 8,
                        &Vs[buf][w * 8 + i * 4][0]);
        }
    };

    for (int pass = 0; pass < 2; pass++) {
        const int it = pass ? xpair : (31 - xpair);   // heavy tile first
        const int i0 = it * 64;
        const int nj = (it >> 1) + 1;   // staged 128-j tiles

        const int qrow = i0 + wa * 16 + c15;
        bf16x8 qf0 = *reinterpret_cast<const bf16x8*>(&qb[base + (size_t)qrow * 64 + quad * 8]);
        bf16x8 qf1 = *reinterpret_cast<const bf16x8*>(&qb[base + (size_t)qrow * 64 + 32 + quad * 8]);

        float m_st = -1e30f, l_st = 0.f;
        f32x4 Oc[4];
#pragma unroll
        for (int t = 0; t < 4; t++) Oc[t] = (f32x4){0.f, 0.f, 0.f, 0.f};

        __syncthreads();          // prev pass done with Ks/Vs (incl. scratch)
        stage(0, 0);

        for (int sj = 0; sj < nj; sj++) {
            const int cb = sj & 1;
            __syncthreads();      // staging for cb complete
            if (sj < nj - 1) stage(sj + 1, cb ^ 1);

            const int j0 = sj * 128 + grp * 64;   // this group's half
            if (j0 <= i0) {
                bf16x8 kc0[4], kc1[4];
#pragma unroll
                for (int t = 0; t < 4; t++) {
                    kc0[t] = lds_read_swz(Ks[cb], grp * 64 + t * 16 + c15, quad);
                    kc1[t] = lds_read_swz(Ks[cb], grp * 64 + t * 16 + c15, 4 + quad);
                }

                f32x4 sc[4];
#pragma unroll
                for (int t = 0; t < 4; t++) sc[t] = (f32x4){0.f, 0.f, 0.f, 0.f};
                __builtin_amdgcn_s_setprio(1);
#pragma unroll
                for (int t = 0; t < 4; t++) {
                    sc[t] = __builtin_amdgcn_mfma_f32_16x16x32_bf16(kc0[t], qf0, sc[t], 0, 0, 0);
                    sc[t] = __builtin_amdgcn_mfma_f32_16x16x32_bf16(kc1[t], qf1, sc[t], 0, 0, 0);
                }
                __builtin_amdgcn_s_setprio(0);

                bf16x8 vv0[4], vv1[4];
#pragma unroll
                for (int t = 0; t < 4; t++) {
                    vv0[t] = lds_read_swz128(Vs[cb], t * 16 + c15, grp * 8 + quad);
                    vv1[t] = lds_read_swz128(Vs[cb], t * 16 + c15, grp * 8 + 4 + quad);
                }

                if (j0 == i0) {   // diagonal half: causal mask
                    const int gi = i0 + wa * 16 + c15;
#pragma unroll
                    for (int t = 0; t < 4; t++) {
#pragma unroll
                        for (int r = 0; r < 4; r++) {
                            int gj = j0 + t * 16 + quad * 4 + r;
                            if (gj > gi) sc[t][r] = -1e30f;
                        }
                    }
                }

                float x0 = fmaxf(fmaxf(sc[0][0], sc[0][1]), fmaxf(sc[0][2], sc[0][3]));
                float x1 = fmaxf(fmaxf(sc[1][0], sc[1][1]), fmaxf(sc[1][2], sc[1][3]));
                float x2 = fmaxf(fmaxf(sc[2][0], sc[2][1]), fmaxf(sc[2][2], sc[2][3]));
                float x3 = fmaxf(fmaxf(sc[3][0], sc[3][1]), fmaxf(sc[3][2], sc[3][3]));
                float tm = fmaxf(fmaxf(x0, x1), fmaxf(x2, x3));
                tm = fmaxf(tm, __shfl_xor(tm, 16));
                tm = fmaxf(tm, __shfl_xor(tm, 32));

                if (!__all(tm <= m_st + 64.0f)) {   // defer-max
                    float mnew = fmaxf(m_st, tm);
                    float alpha = __expf((m_st - mnew) * C);
                    l_st *= alpha;
#pragma unroll
                    for (int t = 0; t < 4; t++)
#pragma unroll
                        for (int r = 0; r < 4; r++) Oc[t][r] *= alpha;
                    m_st = mnew;
                }

                const float mC = m_st * C;
                float p[4][4];
#pragma unroll
                for (int t = 0; t < 4; t++)
#pragma unroll
                    for (int r = 0; r < 4; r++)
                        p[t][r] = __expf(__builtin_fmaf(sc[t][r], C, -mC));

                float s0 = (p[0][0] + p[0][1]) + (p[0][2] + p[0][3]);
                float s1 = (p[1][0] + p[1][1]) + (p[1][2] + p[1][3]);
                float s2 = (p[2][0] + p[2][1]) + (p[2][2] + p[2][3]);
                float s3 = (p[3][0] + p[3][1]) + (p[3][2] + p[3][3]);
                l_st += (s0 + s1) + (s2 + s3);

                unsigned int pk[4][2];
#pragma unroll
                for (int t = 0; t < 4; t++)
#pragma unroll
                    for (int hh = 0; hh < 2; hh++)
                        asm("v_cvt_pk_bf16_f32 %0, %1, %2"
                            : "=v"(pk[t][hh]) : "v"(p[t][2 * hh]), "v"(p[t][2 * hh + 1]));

                unsigned int w0[4], w1[4];
#pragma unroll
                for (int e = 0; e < 4; e++) {
                    int sl = c15 + 16 * ((2 * quad + (e >> 1)) & 3);
                    unsigned int a0 = (unsigned int)__shfl((int)pk[0][e & 1], sl);
                    unsigned int b0 = (unsigned int)__shfl((int)pk[1][e & 1], sl);
                    w0[e] = (quad >> 1) ? b0 : a0;
                    unsigned int a1 = (unsigned int)__shfl((int)pk[2][e & 1], sl);
                    unsigned int b1 = (unsigned int)__shfl((int)pk[3][e & 1], sl);
                    w1[e] = (quad >> 1) ? b1 : a1;
                }
                uint4 u0 = make_uint4(w0[0], w0[1], w0[2], w0[3]);
                uint4 u1 = make_uint4(w1[0], w1[1], w1[2], w1[3]);
                bf16x8 ap0 = *reinterpret_cast<bf16x8*>(&u0);
                bf16x8 ap1 = *reinterpret_cast<bf16x8*>(&u1);

                __builtin_amdgcn_s_setprio(1);
#pragma unroll
                for (int t = 0; t < 4; t++) {
                    Oc[t] = __builtin_amdgcn_mfma_f32_16x16x32_bf16(vv0[t], ap0, Oc[t], 0, 0, 0);
                    Oc[t] = __builtin_amdgcn_mfma_f32_16x16x32_bf16(vv1[t], ap1, Oc[t], 0, 0, 0);
                }
                __builtin_amdgcn_s_setprio(0);
            }
        }

        // -------- combine groups (split-K flash merge) --------
        __syncthreads();
        float l_row = l_st;
        l_row += __shfl_xor(l_row, 16);
        l_row += __shfl_xor(l_row, 32);
        const int q = wa * 16 + c15;

        if (grp == 1) {
#pragma unroll
            for (int t = 0; t < 4; t++)
#pragma unroll
                for (int r = 0; r < 4; r++)
                    exch[q * 65 + t * 16 + quad * 4 + r] = Oc[t][r];
            if (quad == 0) ml[q] = make_float2(m_st, l_row);
        }
        __syncthreads();
        if (grp == 0) {
            float2 mlB = ml[q];
            float m = fmaxf(m_st, mlB.x);
            float aA = __expf((m_st - m) * C);
            float aB = __expf((mlB.x - m) * C);
            float inv = 1.0f / (l_row * aA + mlB.y * aB);
#pragma unroll
            for (int t = 0; t < 4; t++) {
#pragma unroll
                for (int hh = 0; hh < 2; hh++) {
                    float o0 = (Oc[t][2 * hh] * aA
                                + exch[q * 65 + t * 16 + quad * 4 + 2 * hh] * aB) * inv;
                    float o1 = (Oc[t][2 * hh + 1] * aA
                                + exch[q * 65 + t * 16 + quad * 4 + 2 * hh + 1] * aB) * inv;
                    unsigned int pko = (unsigned int)f2bf(o0) | ((unsigned int)f2bf(o1) << 16);
                    *reinterpret_cast<unsigned int*>(
                        &ost[q * 72 + t * 16 + quad * 4 + 2 * hh]) = pko;
                }
            }
            {
                int row = lane >> 2;
                int ch = lane & 3;
                int gi = i0 + wa * 16 + row;
                size_t ob = ((size_t)b * SEQ + gi) * 1024 + h * 64 + ch * 16;
                uint4 v0 = *reinterpret_cast<const uint4*>(&ost[(wa * 16 + row) * 72 + ch * 16]);
                uint4 v1 = *reinterpret_cast<const uint4*>(&ost[(wa * 16 + row) * 72 + ch * 16 + 8]);
                *reinterpret_cast<uint4*>(&ab[ob]) = v0;
                *reinterpret_cast<uint4*>(&ab[ob + 8]) = v1;
            }
        }
    }
}

// MFMA NT-GEMM: out[m,n] = sum_i ab[m,i] * Wo[n,i]; bf16 in, fp32 out.
// 64x128 tile, BK=32 (24KB LDS), 512 blocks.
__global__ __launch_bounds__(256) void out_mfma_kernel(
    const unsigned short* __restrict__ A, const unsigned short* __restrict__ Wob,
    float* __restrict__ out)
{
    const int lin = blockIdx.x;
    const int b = lin & 7;
    const int y = lin >> 3;       // 0..63
    const int m0 = y * 64;
    const int n0g = b * 128;

    __shared__ __align__(16) unsigned short As[2][64][32];    // 8 KB
    __shared__ __align__(16) unsigned short Bs[2][128][32];   // 16 KB

    const int tid = threadIdx.x;
    const int w = tid >> 6;
    const int lane = tid & 63;
    const int quad = lane >> 4;
    const int c15 = lane & 15;
    const int qm = w >> 1, qn = w & 1;
    const int srow4 = lane >> 2;
    const int sch4 = lane & 3;

    auto stage = [&](int k0, int buf) {
        {
            const int row = w * 16 + srow4;
            const int ch = sch4 ^ ((row >> 1) & 3);
            gload_lds16(A + (size_t)(m0 + row) * 1024 + k0 + ch * 8,
                        &As[buf][w * 16][0]);
        }
#pragma unroll
        for (int i = 0; i < 2; i++) {
            const int row = i * 64 + w * 16 + srow4;
            const int ch = sch4 ^ ((row >> 1) & 3);
            gload_lds16(Wob + (size_t)(n0g + row) * 1024 + k0 + ch * 8,
                        &Bs[buf][i * 64 + w * 16][0]);
        }
    };

    f32x4 acc[2][4];
#pragma unroll
    for (int mi = 0; mi < 2; mi++)
#pragma unroll
        for (int ni = 0; ni < 4; ni++) acc[mi][ni] = (f32x4){0.f, 0.f, 0.f, 0.f};

    stage(0, 0);
    for (int k0 = 0; k0 < 1024; k0 += 32) {
        const int cb = (k0 >> 5) & 1;
        __syncthreads();
        if (k0 < 992) stage(k0 + 32, cb ^ 1);

        bf16x8 af[2], bfr[4];
#pragma unroll
        for (int mi = 0; mi < 2; mi++)
            af[mi] = lds_read_swz32(As[cb], qm * 32 + mi * 16 + c15, quad);
#pragma unroll
        for (int ni = 0; ni < 4; ni++)
            bfr[ni] = lds_read_swz32(Bs[cb], qn * 64 + ni * 16 + c15, quad);
#pragma unroll
        for (int mi = 0; mi < 2; mi++)
#pragma unroll
            for (int ni = 0; ni < 4; ni++)
                acc[mi][ni] = __builtin_amdgcn_mfma_f32_16x16x32_bf16(af[mi], bfr[ni], acc[mi][ni], 0, 0, 0);
    }

#pragma unroll
    for (int mi = 0; mi < 2; mi++) {
#pragma unroll
        for (int r = 0; r < 4; r++) {
            int m = m0 + qm * 32 + mi * 16 + quad * 4 + r;
#pragma unroll
            for (int ni = 0; ni < 4; ni++) {
                int n = n0g + qn * 64 + ni * 16 + c15;
                out[(size_t)m * 1024 + n] = acc[mi][ni][r];
            }
        }
    }
}

extern "C" void kernel_launch(void* const* d_in, const int* in_sizes, int n_in,
                              void* d_out, int out_size, void* d_ws, size_t ws_size,
                              hipStream_t stream)
{
    const float* x  = (const float*)d_in[0];
    const float* Wq = (const float*)d_in[1];
    const float* Wk = (const float*)d_in[2];
    const float* Wv = (const float*)d_in[3];
    const float* Wo = (const float*)d_in[4];
    float* out = (float*)d_out;

    const size_t QKV_ELEMS = (size_t)BATCH * SEQ * D_MODEL;  // 4194304

    unsigned short* qb = (unsigned short*)d_ws;
    unsigned short* kb = qb + QKV_ELEMS;
    unsigned short* vt = kb + QKV_ELEMS;   // [b][h][d][s]
    unsigned short* ab = vt + QKV_ELEMS;
    unsigned short* w3bf = ab;             // dead during qkv
    unsigned short* wobf = qb;             // dead during out
    unsigned short* xbuf = (unsigned short*)d_out;               // first 8MB of out
    float2* tab = (float2*)((char*)d_out + 8 * 1024 * 1024);     // 512 KB after xbuf

    conv4_kernel<<<dim3(7424), 256, 0, stream>>>(x, Wq, Wk, Wv, xbuf, w3bf, tab);
    qkv_mfma_kernel<<<dim3(768), 256, 0, stream>>>(xbuf, w3bf, tab, qb, kb, vt);
    attn_kernel<<<dim3(32, 16), 512, 0, stream>>>(qb, kb, vt, ab);
    conv_kernel<<<dim3(1024), 256, 0, stream>>>(Wo, wobf, 262144);
    out_mfma_kernel<<<dim3(512), 256, 0, stream>>>(ab, wobf, out);
}

// Round 15
// 197.765 us; speedup vs baseline: 1.0095x; 1.0095x over previous
//
#include <hip/hip_runtime.h>

#define D_MODEL 1024
#define NUM_HEADS 16
#define SEQ 2048
#define BATCH 2

typedef __attribute__((ext_vector_type(8))) short bf16x8;
typedef __attribute__((ext_vector_type(4))) float f32x4;

__device__ __forceinline__ float bf2f(unsigned short u) {
    return __uint_as_float(((unsigned int)u) << 16);
}
__device__ __forceinline__ unsigned short f2bf(float f) {
    unsigned int u = __float_as_uint(f);
    return (unsigned short)((u + 0x7FFFu + ((u >> 16) & 1u)) >> 16);   // RTNE
}
__device__ __forceinline__ ushort4 pack4(float4 v) {
    return make_ushort4(f2bf(v.x), f2bf(v.y), f2bf(v.z), f2bf(v.w));
}

// async global->LDS, 16B per lane. LDS dest = wave-uniform base + lane*16.
__device__ __forceinline__ void gload_lds16(const unsigned short* g, unsigned short* l) {
    __builtin_amdgcn_global_load_lds(
        (const __attribute__((address_space(1))) unsigned int*)g,
        (__attribute__((address_space(3))) unsigned int*)l,
        16, 0, 0);
}

// Swizzled 16B read from a [N][64] bf16 LDS tile (128B rows, 8 chunks).
__device__ __forceinline__ bf16x8 lds_read_swz(const unsigned short (*tile)[64], int row, int chunk) {
    const char* p = reinterpret_cast<const char*>(tile);
    return *reinterpret_cast<const bf16x8*>(p + row * 128 + (((chunk ^ (row & 7))) << 4));
}

// 64B rows (BK=32 tiles, 4 chunks). XOR (row>>1)&3 (R10 fix: row&3 gave
// 4-way conflicts; (parity,slot) must cover all 8 combos across 16 rows).
__device__ __forceinline__ bf16x8 lds_read_swz32(const unsigned short (*tile)[32], int row, int chunk) {
    const char* p = reinterpret_cast<const char*>(tile);
    return *reinterpret_cast<const bf16x8*>(p + row * 64 + (((chunk ^ ((row >> 1) & 3))) << 4));
}

// Same pattern for 256B rows (128-wide bf16 tiles, 16 chunks, XOR row&15).
__device__ __forceinline__ bf16x8 lds_read_swz128(const unsigned short (*tile)[128], int row, int chunk) {
    const char* p = reinterpret_cast<const char*>(tile);
    return *reinterpret_cast<const bf16x8*>(p + row * 256 + (((chunk ^ (row & 15))) << 4));
}

// fp32 -> bf16 bulk convert (one float4 -> ushort4 per thread).
__global__ __launch_bounds__(256) void conv_kernel(
    const float* __restrict__ src, unsigned short* __restrict__ dst, int n4)
{
    int i = blockIdx.x * 256 + threadIdx.x;
    if (i < n4) {
        float4 v = reinterpret_cast<const float4*>(src)[i];
        reinterpret_cast<ushort4*>(dst)[i] = pack4(v);
    }
}

// Fused conversion of x + Wq/Wk/Wv + RoPE cos/sin table build.
__global__ __launch_bounds__(256) void conv4_kernel(
    const float* __restrict__ x, const float* __restrict__ Wq,
    const float* __restrict__ Wk, const float* __restrict__ Wv,
    unsigned short* __restrict__ xb, unsigned short* __restrict__ w3bf,
    float2* __restrict__ tab)
{
    int i = blockIdx.x * 256 + threadIdx.x;
    if (i < 1835008) {
        const float* src;
        unsigned short* dst;
        int off;
        if (i < 1048576) {
            src = x; dst = xb; off = i;
        } else {
            int j = i - 1048576;
            int which = j >> 18;            // 262144 = 2^18
            off = j & 0x3FFFF;
            src = (which == 0) ? Wq : (which == 1) ? Wk : Wv;
            dst = w3bf + ((size_t)which << 20);
        }
        float4 v = reinterpret_cast<const float4*>(src)[off];
        reinterpret_cast<ushort4*>(dst)[off] = pack4(v);
    } else {
        int idx = i - 1835008;              // 65536 entries
        int s = idx >> 5, d2 = idx & 31;
        float inv = powf(10000.0f, -(float)d2 / 32.0f);
        float sn, cs;
        sincosf((float)s * inv, &sn, &cs);
        tab[idx] = make_float2(cs, sn);
    }
}

// MFMA NT-GEMM: C[m,n] = sum_i xb[m,i] * W[n,i], all bf16.
// 128x128 tile, BK=32, 32KB LDS double-buffer, 3 blocks/CU. (R14's 3-buffer
// counted-vmcnt pipeline regressed: VALUBusy 15->39%, the asm clobbers +
// %3 indexing defeated the compiler's scheduling — m141 failure mode.)
__global__ __launch_bounds__(256) void qkv_mfma_kernel(
    const unsigned short* __restrict__ xb,
    const unsigned short* __restrict__ w3,
    const float2* __restrict__ tab,
    unsigned short* __restrict__ qb, unsigned short* __restrict__ kb,
    unsigned short* __restrict__ vt)
{
    const int lin = blockIdx.x;
    const int b = lin & 7;
    const int t = lin >> 3;
    const int which = t % 3;
    const int y = t / 3;
    const unsigned short* __restrict__ W = w3 + (size_t)which * 1048576;
    const int m0 = y * 128;
    const int n0g = b * 128;

    __shared__ __align__(16) unsigned short As[2][128][32];
    __shared__ __align__(16) unsigned short Bs[2][128][32];

    const int tid = threadIdx.x;
    const int w = tid >> 6;
    const int lane = tid & 63;
    const int quad = lane >> 4;
    const int c15 = lane & 15;
    const int qm = w >> 1, qn = w & 1;
    const int srow4 = lane >> 2;
    const int sch4 = lane & 3;

    auto stage = [&](int k0, int buf) {
#pragma unroll
        for (int i = 0; i < 2; i++) {
            const int row = i * 64 + w * 16 + srow4;
            const int ch = sch4 ^ ((row >> 1) & 3);
            gload_lds16(xb + (size_t)(m0 + row) * 1024 + k0 + ch * 8,
                        &As[buf][i * 64 + w * 16][0]);
            gload_lds16(W + (size_t)(n0g + row) * 1024 + k0 + ch * 8,
                        &Bs[buf][i * 64 + w * 16][0]);
        }
    };

    f32x4 acc[4][4];
#pragma unroll
    for (int mi = 0; mi < 4; mi++)
#pragma unroll
        for (int ni = 0; ni < 4; ni++) acc[mi][ni] = (f32x4){0.f, 0.f, 0.f, 0.f};

    stage(0, 0);
    for (int k0 = 0; k0 < 1024; k0 += 32) {
        const int cb = (k0 >> 5) & 1;
        __syncthreads();
        if (k0 < 992) stage(k0 + 32, cb ^ 1);

        bf16x8 af[4], bfr[4];
#pragma unroll
        for (int mi = 0; mi < 4; mi++)
            af[mi] = lds_read_swz32(As[cb], qm * 64 + mi * 16 + c15, quad);
#pragma unroll
        for (int ni = 0; ni < 4; ni++)
            bfr[ni] = lds_read_swz32(Bs[cb], qn * 64 + ni * 16 + c15, quad);
#pragma unroll
        for (int mi = 0; mi < 4; mi++)
#pragma unroll
            for (int ni = 0; ni < 4; ni++)
                acc[mi][ni] = __builtin_amdgcn_mfma_f32_16x16x32_bf16(af[mi], bfr[ni], acc[mi][ni], 0, 0, 0);
    }

    __syncthreads();
    unsigned short* stg = &As[0][0][0] + w * (16 * 72);
    const int hq = b * 2 + qn;
    unsigned short* outp = (which == 0) ? qb : kb;
    const int odd = c15 & 1;

#pragma unroll
    for (int mi = 0; mi < 4; mi++) {
#pragma unroll
        for (int r = 0; r < 4; r++) {
            int m = m0 + qm * 64 + mi * 16 + quad * 4 + r;
            int s = m & (SEQ - 1);
            const float2* trow = tab + (s << 5);
#pragma unroll
            for (int ni = 0; ni < 4; ni++) {
                float val = acc[mi][ni][r];
                float res;
                if (which < 2) {
                    float part = __shfl_xor(val, 1);
                    float2 cs = trow[(ni * 16 + c15) >> 1];
                    res = odd ? (part * cs.y + val * cs.x) : (val * cs.x - part * cs.y);
                } else {
                    res = val;
                }
                stg[(quad * 4 + r) * 72 + ni * 16 + c15] = f2bf(res);
            }
        }
        if (which < 2) {
            int row = lane >> 2;
            int ch = lane & 3;
            int m = m0 + qm * 64 + mi * 16 + row;
            int s = m & (SEQ - 1);
            int bb = m >> 11;
            size_t ob = (((size_t)bb * NUM_HEADS + hq) * SEQ + s) * 64 + ch * 16;
            uint4 v0 = *reinterpret_cast<const uint4*>(&stg[row * 72 + ch * 16]);
            uint4 v1 = *reinterpret_cast<const uint4*>(&stg[row * 72 + ch * 16 + 8]);
            *reinterpret_cast<uint4*>(&outp[ob]) = v0;
            *reinterpret_cast<uint4*>(&outp[ob + 8]) = v1;
        } else {
            int mbase = m0 + qm * 64 + mi * 16;
            int bb = mbase >> 11;
            int s_base = mbase & (SEQ - 1);
            unsigned short tmp[16];
#pragma unroll
            for (int sl = 0; sl < 16; sl++) tmp[sl] = stg[sl * 72 + lane];
            size_t ob = (((size_t)bb * NUM_HEADS + hq) * 64 + lane) * SEQ + s_base;
            *reinterpret_cast<uint4*>(&vt[ob])     = *reinterpret_cast<uint4*>(&tmp[0]);
            *reinterpret_cast<uint4*>(&vt[ob + 8]) = *reinterpret_cast<uint4*>(&tmp[8]);
        }
    }
}

// MFMA flash attention, 8-wave blocks with j-split wave groups.
// Grid is (bh, xpair) so the 16 blocks sharing one bh's K/V panel land on
// one XCD (lin == bh mod 8) -> panel re-reads are L2 hits (T1).
__global__ __launch_bounds__(512, 4) void attn_kernel(
    const unsigned short* __restrict__ qb, const unsigned short* __restrict__ kb,
    const unsigned short* __restrict__ vt, unsigned short* __restrict__ ab)
{
    const int xpair = blockIdx.y;   // 0..15
    const int bh = blockIdx.x;      // 0..31 (fast dim -> XCD clustering)
    const int b = bh >> 4, h = bh & 15;
    const size_t base = (size_t)bh * SEQ * 64;     // qb/kb [b][h][s][d]
    const size_t vbase = (size_t)bh * 64 * SEQ;    // vt [b][h][d][s]
    const int tid = threadIdx.x;
    const int w = tid >> 6;        // 0..7
    const int grp = w >> 2;        // 0 = A (low half), 1 = B (high half)
    const int wa = w & 3;          // wave-in-group; q-rows wa*16..+16
    const int lane = tid & 63;
    const int quad = lane >> 4;
    const int c15 = lane & 15;
    const int srow8 = lane >> 3;
    const int sch = lane & 7;
    const int srow16 = lane >> 4;
    const int sch16 = lane & 15;
    const float C = 0.125f;

    __shared__ __align__(16) unsigned short Ks[2][128][64];   // [buf][j][d], 32 KB
    __shared__ __align__(16) unsigned short Vs[2][64][128];   // [buf][d][j], 32 KB
    float* exch = (float*)&Ks[0][0][0];                 // B's O partial [64 q][65]
    float2* ml  = (float2*)((char*)&Ks[0][0][0] + 17152); // B's (m,l) per q
    unsigned short* ost = &Vs[0][0][0];                 // A store staging [64][72]

    auto stage = [&](int sj, int buf) {
        const int j0s = sj * 128;
#pragma unroll
        for (int i = 0; i < 2; i++) {
            const int krow = w * 16 + i * 8 + srow8;
            const int kch = sch ^ (krow & 7);
            gload_lds16(kb + base + (size_t)(j0s + krow) * 64 + kch * 8,
                        &Ks[buf][w * 16 + i * 8][0]);
            const int vrow = w * 8 + i * 4 + srow16;
            const int vch = sch16 ^ (vrow & 15);
            gload_lds16(vt + vbase + (size_t)vrow * SEQ + j0s + vch * 8,
                        &Vs[buf][w * 8 + i * 4][0]);
        }
    };

    for (int pass = 0; pass < 2; pass++) {
        const int it = pass ? xpair : (31 - xpair);   // heavy tile first
        const int i0 = it * 64;
        const int nj = (it >> 1) + 1;   // staged 128-j tiles

        const int qrow = i0 + wa * 16 + c15;
        bf16x8 qf0 = *reinterpret_cast<const bf16x8*>(&qb[base + (size_t)qrow * 64 + quad * 8]);
        bf16x8 qf1 = *reinterpret_cast<const bf16x8*>(&qb[base + (size_t)qrow * 64 + 32 + quad * 8]);

        float m_st = -1e30f, l_st = 0.f;
        f32x4 Oc[4];
#pragma unroll
        for (int t = 0; t < 4; t++) Oc[t] = (f32x4){0.f, 0.f, 0.f, 0.f};

        __syncthreads();          // prev pass done with Ks/Vs (incl. scratch)
        stage(0, 0);

        for (int sj = 0; sj < nj; sj++) {
            const int cb = sj & 1;
            __syncthreads();      // staging for cb complete
            if (sj < nj - 1) stage(sj + 1, cb ^ 1);

            const int j0 = sj * 128 + grp * 64;   // this group's half
            if (j0 <= i0) {
                bf16x8 kc0[4], kc1[4];
#pragma unroll
                for (int t = 0; t < 4; t++) {
                    kc0[t] = lds_read_swz(Ks[cb], grp * 64 + t * 16 + c15, quad);
                    kc1[t] = lds_read_swz(Ks[cb], grp * 64 + t * 16 + c15, 4 + quad);
                }

                f32x4 sc[4];
#pragma unroll
                for (int t = 0; t < 4; t++) sc[t] = (f32x4){0.f, 0.f, 0.f, 0.f};
                __builtin_amdgcn_s_setprio(1);
#pragma unroll
                for (int t = 0; t < 4; t++) {
                    sc[t] = __builtin_amdgcn_mfma_f32_16x16x32_bf16(kc0[t], qf0, sc[t], 0, 0, 0);
                    sc[t] = __builtin_amdgcn_mfma_f32_16x16x32_bf16(kc1[t], qf1, sc[t], 0, 0, 0);
                }
                __builtin_amdgcn_s_setprio(0);

                bf16x8 vv0[4], vv1[4];
#pragma unroll
                for (int t = 0; t < 4; t++) {
                    vv0[t] = lds_read_swz128(Vs[cb], t * 16 + c15, grp * 8 + quad);
                    vv1[t] = lds_read_swz128(Vs[cb], t * 16 + c15, grp * 8 + 4 + quad);
                }

                if (j0 == i0) {   // diagonal half: causal mask
                    const int gi = i0 + wa * 16 + c15;
#pragma unroll
                    for (int t = 0; t < 4; t++) {
#pragma unroll
                        for (int r = 0; r < 4; r++) {
                            int gj = j0 + t * 16 + quad * 4 + r;
                            if (gj > gi) sc[t][r] = -1e30f;
                        }
                    }
                }

                float x0 = fmaxf(fmaxf(sc[0][0], sc[0][1]), fmaxf(sc[0][2], sc[0][3]));
                float x1 = fmaxf(fmaxf(sc[1][0], sc[1][1]), fmaxf(sc[1][2], sc[1][3]));
                float x2 = fmaxf(fmaxf(sc[2][0], sc[2][1]), fmaxf(sc[2][2], sc[2][3]));
                float x3 = fmaxf(fmaxf(sc[3][0], sc[3][1]), fmaxf(sc[3][2], sc[3][3]));
                float tm = fmaxf(fmaxf(x0, x1), fmaxf(x2, x3));
                tm = fmaxf(tm, __shfl_xor(tm, 16));
                tm = fmaxf(tm, __shfl_xor(tm, 32));

                if (!__all(tm <= m_st + 64.0f)) {   // defer-max
                    float mnew = fmaxf(m_st, tm);
                    float alpha = __expf((m_st - mnew) * C);
                    l_st *= alpha;
#pragma unroll
                    for (int t = 0; t < 4; t++)
#pragma unroll
                        for (int r = 0; r < 4; r++) Oc[t][r] *= alpha;
                    m_st = mnew;
                }

                const float mC = m_st * C;
                float p[4][4];
#pragma unroll
                for (int t = 0; t < 4; t++)
#pragma unroll
                    for (int r = 0; r < 4; r++)
                        p[t][r] = __expf(__builtin_fmaf(sc[t][r], C, -mC));

                float s0 = (p[0][0] + p[0][1]) + (p[0][2] + p[0][3]);
                float s1 = (p[1][0] + p[1][1]) + (p[1][2] + p[1][3]);
                float s2 = (p[2][0] + p[2][1]) + (p[2][2] + p[2][3]);
                float s3 = (p[3][0] + p[3][1]) + (p[3][2] + p[3][3]);
                l_st += (s0 + s1) + (s2 + s3);

                unsigned int pk[4][2];
#pragma unroll
                for (int t = 0; t < 4; t++)
#pragma unroll
                    for (int hh = 0; hh < 2; hh++)
                        asm("v_cvt_pk_bf16_f32 %0, %1, %2"
                            : "=v"(pk[t][hh]) : "v"(p[t][2 * hh]), "v"(p[t][2 * hh + 1]));

                unsigned int w0[4], w1[4];
#pragma unroll
                for (int e = 0; e < 4; e++) {
                    int sl = c15 + 16 * ((2 * quad + (e >> 1)) & 3);
                    unsigned int a0 = (unsigned int)__shfl((int)pk[0][e & 1], sl);
                    unsigned int b0 = (unsigned int)__shfl((int)pk[1][e & 1], sl);
                    w0[e] = (quad >> 1) ? b0 : a0;
                    unsigned int a1 = (unsigned int)__shfl((int)pk[2][e & 1], sl);
                    unsigned int b1 = (unsigned int)__shfl((int)pk[3][e & 1], sl);
                    w1[e] = (quad >> 1) ? b1 : a1;
                }
                uint4 u0 = make_uint4(w0[0], w0[1], w0[2], w0[3]);
                uint4 u1 = make_uint4(w1[0], w1[1], w1[2], w1[3]);
                bf16x8 ap0 = *reinterpret_cast<bf16x8*>(&u0);
                bf16x8 ap1 = *reinterpret_cast<bf16x8*>(&u1);

                __builtin_amdgcn_s_setprio(1);
#pragma unroll
                for (int t = 0; t < 4; t++) {
                    Oc[t] = __builtin_amdgcn_mfma_f32_16x16x32_bf16(vv0[t], ap0, Oc[t], 0, 0, 0);
                    Oc[t] = __builtin_amdgcn_mfma_f32_16x16x32_bf16(vv1[t], ap1, Oc[t], 0, 0, 0);
                }
                __builtin_amdgcn_s_setprio(0);
            }
        }

        // -------- combine groups (split-K flash merge) --------
        __syncthreads();
        float l_row = l_st;
        l_row += __shfl_xor(l_row, 16);
        l_row += __shfl_xor(l_row, 32);
        const int q = wa * 16 + c15;

        if (grp == 1) {
#pragma unroll
            for (int t = 0; t < 4; t++)
#pragma unroll
                for (int r = 0; r < 4; r++)
                    exch[q * 65 + t * 16 + quad * 4 + r] = Oc[t][r];
            if (quad == 0) ml[q] = make_float2(m_st, l_row);
        }
        __syncthreads();
        if (grp == 0) {
            float2 mlB = ml[q];
            float m = fmaxf(m_st, mlB.x);
            float aA = __expf((m_st - m) * C);
            float aB = __expf((mlB.x - m) * C);
            float inv = 1.0f / (l_row * aA + mlB.y * aB);
#pragma unroll
            for (int t = 0; t < 4; t++) {
#pragma unroll
                for (int hh = 0; hh < 2; hh++) {
                    float o0 = (Oc[t][2 * hh] * aA
                                + exch[q * 65 + t * 16 + quad * 4 + 2 * hh] * aB) * inv;
                    float o1 = (Oc[t][2 * hh + 1] * aA
                                + exch[q * 65 + t * 16 + quad * 4 + 2 * hh + 1] * aB) * inv;
                    unsigned int pko = (unsigned int)f2bf(o0) | ((unsigned int)f2bf(o1) << 16);
                    *reinterpret_cast<unsigned int*>(
                        &ost[q * 72 + t * 16 + quad * 4 + 2 * hh]) = pko;
                }
            }
            {
                int row = lane >> 2;
                int ch = lane & 3;
                int gi = i0 + wa * 16 + row;
                size_t ob = ((size_t)b * SEQ + gi) * 1024 + h * 64 + ch * 16;
                uint4 v0 = *reinterpret_cast<const uint4*>(&ost[(wa * 16 + row) * 72 + ch * 16]);
                uint4 v1 = *reinterpret_cast<const uint4*>(&ost[(wa * 16 + row) * 72 + ch * 16 + 8]);
                *reinterpret_cast<uint4*>(&ab[ob]) = v0;
                *reinterpret_cast<uint4*>(&ab[ob + 8]) = v1;
            }
        }
    }
}

// MFMA NT-GEMM: out[m,n] = sum_i ab[m,i] * Wo[n,i]; bf16 in, fp32 out.
// 64x128 tile, BK=32 (24KB LDS), 512 blocks.
__global__ __launch_bounds__(256) void out_mfma_kernel(
    const unsigned short* __restrict__ A, const unsigned short* __restrict__ Wob,
    float* __restrict__ out)
{
    const int lin = blockIdx.x;
    const int b = lin & 7;
    const int y = lin >> 3;       // 0..63
    const int m0 = y * 64;
    const int n0g = b * 128;

    __shared__ __align__(16) unsigned short As[2][64][32];    // 8 KB
    __shared__ __align__(16) unsigned short Bs[2][128][32];   // 16 KB

    const int tid = threadIdx.x;
    const int w = tid >> 6;
    const int lane = tid & 63;
    const int quad = lane >> 4;
    const int c15 = lane & 15;
    const int qm = w >> 1, qn = w & 1;
    const int srow4 = lane >> 2;
    const int sch4 = lane & 3;

    auto stage = [&](int k0, int buf) {
        {
            const int row = w * 16 + srow4;
            const int ch = sch4 ^ ((row >> 1) & 3);
            gload_lds16(A + (size_t)(m0 + row) * 1024 + k0 + ch * 8,
                        &As[buf][w * 16][0]);
        }
#pragma unroll
        for (int i = 0; i < 2; i++) {
            const int row = i * 64 + w * 16 + srow4;
            const int ch = sch4 ^ ((row >> 1) & 3);
            gload_lds16(Wob + (size_t)(n0g + row) * 1024 + k0 + ch * 8,
                        &Bs[buf][i * 64 + w * 16][0]);
        }
    };

    f32x4 acc[2][4];
#pragma unroll
    for (int mi = 0; mi < 2; mi++)
#pragma unroll
        for (int ni = 0; ni < 4; ni++) acc[mi][ni] = (f32x4){0.f, 0.f, 0.f, 0.f};

    stage(0, 0);
    for (int k0 = 0; k0 < 1024; k0 += 32) {
        const int cb = (k0 >> 5) & 1;
        __syncthreads();
        if (k0 < 992) stage(k0 + 32, cb ^ 1);

        bf16x8 af[2], bfr[4];
#pragma unroll
        for (int mi = 0; mi < 2; mi++)
            af[mi] = lds_read_swz32(As[cb], qm * 32 + mi * 16 + c15, quad);
#pragma unroll
        for (int ni = 0; ni < 4; ni++)
            bfr[ni] = lds_read_swz32(Bs[cb], qn * 64 + ni * 16 + c15, quad);
#pragma unroll
        for (int mi = 0; mi < 2; mi++)
#pragma unroll
            for (int ni = 0; ni < 4; ni++)
                acc[mi][ni] = __builtin_amdgcn_mfma_f32_16x16x32_bf16(af[mi], bfr[ni], acc[mi][ni], 0, 0, 0);
    }

#pragma unroll
    for (int mi = 0; mi < 2; mi++) {
#pragma unroll
        for (int r = 0; r < 4; r++) {
            int m = m0 + qm * 32 + mi * 16 + quad * 4 + r;
#pragma unroll
            for (int ni = 0; ni < 4; ni++) {
                int n = n0g + qn * 64 + ni * 16 + c15;
                out[(size_t)m * 1024 + n] = acc[mi][ni][r];
            }
        }
    }
}

extern "C" void kernel_launch(void* const* d_in, const int* in_sizes, int n_in,
                              void* d_out, int out_size, void* d_ws, size_t ws_size,
                              hipStream_t stream)
{
    const float* x  = (const float*)d_in[0];
    const float* Wq = (const float*)d_in[1];
    const float* Wk = (const float*)d_in[2];
    const float* Wv = (const float*)d_in[3];
    const float* Wo = (const float*)d_in[4];
    float* out = (float*)d_out;

    const size_t QKV_ELEMS = (size_t)BATCH * SEQ * D_MODEL;  // 4194304

    unsigned short* qb = (unsigned short*)d_ws;
    unsigned short* kb = qb + QKV_ELEMS;
    unsigned short* vt = kb + QKV_ELEMS;   // [b][h][d][s]
    unsigned short* ab = vt + QKV_ELEMS;
    unsigned short* w3bf = ab;             // dead during qkv
    unsigned short* wobf = qb;             // dead during out
    unsigned short* xbuf = (unsigned short*)d_out;               // first 8MB of out
    float2* tab = (float2*)((char*)d_out + 8 * 1024 * 1024);     // 512 KB after xbuf

    conv4_kernel<<<dim3(7424), 256, 0, stream>>>(x, Wq, Wk, Wv, xbuf, w3bf, tab);
    qkv_mfma_kernel<<<dim3(768), 256, 0, stream>>>(xbuf, w3bf, tab, qb, kb, vt);
    attn_kernel<<<dim3(32, 16), 512, 0, stream>>>(qb, kb, vt, ab);
    conv_kernel<<<dim3(1024), 256, 0, stream>>>(Wo, wobf, 262144);
    out_mfma_kernel<<<dim3(512), 256, 0, stream>>>(ab, wobf, out);
}

// Round 16
// 194.190 us; speedup vs baseline: 1.0281x; 1.0184x over previous
//
#include <hip/hip_runtime.h>

#define D_MODEL 1024
#define NUM_HEADS 16
#define SEQ 2048
#define BATCH 2

typedef __attribute__((ext_vector_type(8))) short bf16x8;
typedef __attribute__((ext_vector_type(4))) float f32x4;

__device__ __forceinline__ float bf2f(unsigned short u) {
    return __uint_as_float(((unsigned int)u) << 16);
}
__device__ __forceinline__ unsigned short f2bf(float f) {
    unsigned int u = __float_as_uint(f);
    return (unsigned short)((u + 0x7FFFu + ((u >> 16) & 1u)) >> 16);   // RTNE
}
__device__ __forceinline__ ushort4 pack4(float4 v) {
    return make_ushort4(f2bf(v.x), f2bf(v.y), f2bf(v.z), f2bf(v.w));
}

// async global->LDS, 16B per lane. LDS dest = wave-uniform base + lane*16.
__device__ __forceinline__ void gload_lds16(const unsigned short* g, unsigned short* l) {
    __builtin_amdgcn_global_load_lds(
        (const __attribute__((address_space(1))) unsigned int*)g,
        (__attribute__((address_space(3))) unsigned int*)l,
        16, 0, 0);
}

// Swizzled 16B read from a [N][64] bf16 LDS tile (128B rows, 8 chunks).
__device__ __forceinline__ bf16x8 lds_read_swz(const unsigned short (*tile)[64], int row, int chunk) {
    const char* p = reinterpret_cast<const char*>(tile);
    return *reinterpret_cast<const bf16x8*>(p + row * 128 + (((chunk ^ (row & 7))) << 4));
}

// 64B rows (BK=32 tiles, 4 chunks). XOR (row>>1)&3 (R10 fix: row&3 gave
// 4-way conflicts; (parity,slot) must cover all 8 combos across 16 rows).
__device__ __forceinline__ bf16x8 lds_read_swz32(const unsigned short (*tile)[32], int row, int chunk) {
    const char* p = reinterpret_cast<const char*>(tile);
    return *reinterpret_cast<const bf16x8*>(p + row * 64 + (((chunk ^ ((row >> 1) & 3))) << 4));
}

// Same pattern for 256B rows (128-wide bf16 tiles, 16 chunks, XOR row&15).
__device__ __forceinline__ bf16x8 lds_read_swz128(const unsigned short (*tile)[128], int row, int chunk) {
    const char* p = reinterpret_cast<const char*>(tile);
    return *reinterpret_cast<const bf16x8*>(p + row * 256 + (((chunk ^ (row & 15))) << 4));
}

// fp32 -> bf16 bulk convert (one float4 -> ushort4 per thread).
__global__ __launch_bounds__(256) void conv_kernel(
    const float* __restrict__ src, unsigned short* __restrict__ dst, int n4)
{
    int i = blockIdx.x * 256 + threadIdx.x;
    if (i < n4) {
        float4 v = reinterpret_cast<const float4*>(src)[i];
        reinterpret_cast<ushort4*>(dst)[i] = pack4(v);
    }
}

// Fused conversion of x + Wq/Wk/Wv (+ optionally Wo into a dedicated ws
// region, when the workspace has headroom) + RoPE cos/sin table build.
__global__ __launch_bounds__(256) void conv4_kernel(
    const float* __restrict__ x, const float* __restrict__ Wq,
    const float* __restrict__ Wk, const float* __restrict__ Wv,
    const float* __restrict__ Wo,
    unsigned short* __restrict__ xb, unsigned short* __restrict__ w3bf,
    unsigned short* __restrict__ wob,    // nullptr -> skip Wo (fallback path)
    float2* __restrict__ tab)
{
    int i = blockIdx.x * 256 + threadIdx.x;
    const int NW = (wob != nullptr) ? 2097152 : 1835008;
    if (i < NW) {
        const float* src;
        unsigned short* dst;
        int off;
        if (i < 1048576) {
            src = x; dst = xb; off = i;
        } else if (i < 1835008) {
            int j = i - 1048576;
            int which = j >> 18;            // 262144 = 2^18
            off = j & 0x3FFFF;
            src = (which == 0) ? Wq : (which == 1) ? Wk : Wv;
            dst = w3bf + ((size_t)which << 20);
        } else {
            off = i - 1835008;
            src = Wo; dst = wob;
        }
        float4 v = reinterpret_cast<const float4*>(src)[off];
        reinterpret_cast<ushort4*>(dst)[off] = pack4(v);
    } else {
        int idx = i - NW;                   // 65536 entries
        if (idx < 65536) {
            int s = idx >> 5, d2 = idx & 31;
            float inv = powf(10000.0f, -(float)d2 / 32.0f);
            float sn, cs;
            sincosf((float)s * inv, &sn, &cs);
            tab[idx] = make_float2(cs, sn);
        }
    }
}

// MFMA NT-GEMM: C[m,n] = sum_i xb[m,i] * W[n,i], all bf16.
// 128x128 tile, BK=32, 32KB LDS double-buffer, 3 blocks/CU.
__global__ __launch_bounds__(256) void qkv_mfma_kernel(
    const unsigned short* __restrict__ xb,
    const unsigned short* __restrict__ w3,
    const float2* __restrict__ tab,
    unsigned short* __restrict__ qb, unsigned short* __restrict__ kb,
    unsigned short* __restrict__ vt)
{
    const int lin = blockIdx.x;
    const int b = lin & 7;
    const int t = lin >> 3;
    const int which = t % 3;
    const int y = t / 3;
    const unsigned short* __restrict__ W = w3 + (size_t)which * 1048576;
    const int m0 = y * 128;
    const int n0g = b * 128;

    __shared__ __align__(16) unsigned short As[2][128][32];
    __shared__ __align__(16) unsigned short Bs[2][128][32];

    const int tid = threadIdx.x;
    const int w = tid >> 6;
    const int lane = tid & 63;
    const int quad = lane >> 4;
    const int c15 = lane & 15;
    const int qm = w >> 1, qn = w & 1;
    const int srow4 = lane >> 2;
    const int sch4 = lane & 3;

    auto stage = [&](int k0, int buf) {
#pragma unroll
        for (int i = 0; i < 2; i++) {
            const int row = i * 64 + w * 16 + srow4;
            const int ch = sch4 ^ ((row >> 1) & 3);
            gload_lds16(xb + (size_t)(m0 + row) * 1024 + k0 + ch * 8,
                        &As[buf][i * 64 + w * 16][0]);
            gload_lds16(W + (size_t)(n0g + row) * 1024 + k0 + ch * 8,
                        &Bs[buf][i * 64 + w * 16][0]);
        }
    };

    f32x4 acc[4][4];
#pragma unroll
    for (int mi = 0; mi < 4; mi++)
#pragma unroll
        for (int ni = 0; ni < 4; ni++) acc[mi][ni] = (f32x4){0.f, 0.f, 0.f, 0.f};

    stage(0, 0);
    for (int k0 = 0; k0 < 1024; k0 += 32) {
        const int cb = (k0 >> 5) & 1;
        __syncthreads();
        if (k0 < 992) stage(k0 + 32, cb ^ 1);

        bf16x8 af[4], bfr[4];
#pragma unroll
        for (int mi = 0; mi < 4; mi++)
            af[mi] = lds_read_swz32(As[cb], qm * 64 + mi * 16 + c15, quad);
#pragma unroll
        for (int ni = 0; ni < 4; ni++)
            bfr[ni] = lds_read_swz32(Bs[cb], qn * 64 + ni * 16 + c15, quad);
#pragma unroll
        for (int mi = 0; mi < 4; mi++)
#pragma unroll
            for (int ni = 0; ni < 4; ni++)
                acc[mi][ni] = __builtin_amdgcn_mfma_f32_16x16x32_bf16(af[mi], bfr[ni], acc[mi][ni], 0, 0, 0);
    }

    __syncthreads();
    unsigned short* stg = &As[0][0][0] + w * (16 * 72);
    const int hq = b * 2 + qn;
    unsigned short* outp = (which == 0) ? qb : kb;
    const int odd = c15 & 1;

#pragma unroll
    for (int mi = 0; mi < 4; mi++) {
#pragma unroll
        for (int r = 0; r < 4; r++) {
            int m = m0 + qm * 64 + mi * 16 + quad * 4 + r;
            int s = m & (SEQ - 1);
            const float2* trow = tab + (s << 5);
#pragma unroll
            for (int ni = 0; ni < 4; ni++) {
                float val = acc[mi][ni][r];
                float res;
                if (which < 2) {
                    float part = __shfl_xor(val, 1);
                    float2 cs = trow[(ni * 16 + c15) >> 1];
                    res = odd ? (part * cs.y + val * cs.x) : (val * cs.x - part * cs.y);
                } else {
                    res = val;
                }
                stg[(quad * 4 + r) * 72 + ni * 16 + c15] = f2bf(res);
            }
        }
        if (which < 2) {
            int row = lane >> 2;
            int ch = lane & 3;
            int m = m0 + qm * 64 + mi * 16 + row;
            int s = m & (SEQ - 1);
            int bb = m >> 11;
            size_t ob = (((size_t)bb * NUM_HEADS + hq) * SEQ + s) * 64 + ch * 16;
            uint4 v0 = *reinterpret_cast<const uint4*>(&stg[row * 72 + ch * 16]);
            uint4 v1 = *reinterpret_cast<const uint4*>(&stg[row * 72 + ch * 16 + 8]);
            *reinterpret_cast<uint4*>(&outp[ob]) = v0;
            *reinterpret_cast<uint4*>(&outp[ob + 8]) = v1;
        } else {
            int mbase = m0 + qm * 64 + mi * 16;
            int bb = mbase >> 11;
            int s_base = mbase & (SEQ - 1);
            unsigned short tmp[16];
#pragma unroll
            for (int sl = 0; sl < 16; sl++) tmp[sl] = stg[sl * 72 + lane];
            size_t ob = (((size_t)bb * NUM_HEADS + hq) * 64 + lane) * SEQ + s_base;
            *reinterpret_cast<uint4*>(&vt[ob])     = *reinterpret_cast<uint4*>(&tmp[0]);
            *reinterpret_cast<uint4*>(&vt[ob + 8]) = *reinterpret_cast<uint4*>(&tmp[8]);
        }
    }
}

// MFMA flash attention, 8-wave blocks with j-split wave groups.
// Grid is (bh, xpair) so the 16 blocks sharing one bh's K/V panel land on
// one XCD (lin == bh mod 8) -> panel re-reads are L2 hits (T1).
__global__ __launch_bounds__(512, 4) void attn_kernel(
    const unsigned short* __restrict__ qb, const unsigned short* __restrict__ kb,
    const unsigned short* __restrict__ vt, unsigned short* __restrict__ ab)
{
    const int xpair = blockIdx.y;   // 0..15
    const int bh = blockIdx.x;      // 0..31 (fast dim -> XCD clustering)
    const int b = bh >> 4, h = bh & 15;
    const size_t base = (size_t)bh * SEQ * 64;     // qb/kb [b][h][s][d]
    const size_t vbase = (size_t)bh * 64 * SEQ;    // vt [b][h][d][s]
    const int tid = threadIdx.x;
    const int w = tid >> 6;        // 0..7
    const int grp = w >> 2;        // 0 = A (low half), 1 = B (high half)
    const int wa = w & 3;          // wave-in-group; q-rows wa*16..+16
    const int lane = tid & 63;
    const int quad = lane >> 4;
    const int c15 = lane & 15;
    const int srow8 = lane >> 3;
    const int sch = lane & 7;
    const int srow16 = lane >> 4;
    const int sch16 = lane & 15;
    const float C = 0.125f;

    __shared__ __align__(16) unsigned short Ks[2][128][64];   // [buf][j][d], 32 KB
    __shared__ __align__(16) unsigned short Vs[2][64][128];   // [buf][d][j], 32 KB
    float* exch = (float*)&Ks[0][0][0];                 // B's O partial [64 q][65]
    float2* ml  = (float2*)((char*)&Ks[0][0][0] + 17152); // B's (m,l) per q
    unsigned short* ost = &Vs[0][0][0];                 // A store staging [64][72]

    auto stage = [&](int sj, int buf) {
        const int j0s = sj * 128;
#pragma unroll
        for (int i = 0; i < 2; i++) {
            const int krow = w * 16 + i * 8 + srow8;
            const int kch = sch ^ (krow & 7);
            gload_lds16(kb + base + (size_t)(j0s + krow) * 64 + kch * 8,
                        &Ks[buf][w * 16 + i * 8][0]);
            const int vrow = w * 8 + i * 4 + srow16;
            const int vch = sch16 ^ (vrow & 15);
            gload_lds16(vt + vbase + (size_t)vrow * SEQ + j0s + vch * 8,
                        &Vs[buf][w * 8 + i * 4][0]);
        }
    };

    for (int pass = 0; pass < 2; pass++) {
        const int it = pass ? xpair : (31 - xpair);   // heavy tile first
        const int i0 = it * 64;
        const int nj = (it >> 1) + 1;   // staged 128-j tiles

        const int qrow = i0 + wa * 16 + c15;
        bf16x8 qf0 = *reinterpret_cast<const bf16x8*>(&qb[base + (size_t)qrow * 64 + quad * 8]);
        bf16x8 qf1 = *reinterpret_cast<const bf16x8*>(&qb[base + (size_t)qrow * 64 + 32 + quad * 8]);

        float m_st = -1e30f, l_st = 0.f;
        f32x4 Oc[4];
#pragma unroll
        for (int t = 0; t < 4; t++) Oc[t] = (f32x4){0.f, 0.f, 0.f, 0.f};

        __syncthreads();          // prev pass done with Ks/Vs (incl. scratch)
        stage(0, 0);

        for (int sj = 0; sj < nj; sj++) {
            const int cb = sj & 1;
            __syncthreads();      // staging for cb complete
            if (sj < nj - 1) stage(sj + 1, cb ^ 1);

            const int j0 = sj * 128 + grp * 64;   // this group's half
            if (j0 <= i0) {
                bf16x8 kc0[4], kc1[4];
#pragma unroll
                for (int t = 0; t < 4; t++) {
                    kc0[t] = lds_read_swz(Ks[cb], grp * 64 + t * 16 + c15, quad);
                    kc1[t] = lds_read_swz(Ks[cb], grp * 64 + t * 16 + c15, 4 + quad);
                }

                f32x4 sc[4];
#pragma unroll
                for (int t = 0; t < 4; t++) sc[t] = (f32x4){0.f, 0.f, 0.f, 0.f};
                __builtin_amdgcn_s_setprio(1);
#pragma unroll
                for (int t = 0; t < 4; t++) {
                    sc[t] = __builtin_amdgcn_mfma_f32_16x16x32_bf16(kc0[t], qf0, sc[t], 0, 0, 0);
                    sc[t] = __builtin_amdgcn_mfma_f32_16x16x32_bf16(kc1[t], qf1, sc[t], 0, 0, 0);
                }
                __builtin_amdgcn_s_setprio(0);

                bf16x8 vv0[4], vv1[4];
#pragma unroll
                for (int t = 0; t < 4; t++) {
                    vv0[t] = lds_read_swz128(Vs[cb], t * 16 + c15, grp * 8 + quad);
                    vv1[t] = lds_read_swz128(Vs[cb], t * 16 + c15, grp * 8 + 4 + quad);
                }

                if (j0 == i0) {   // diagonal half: causal mask
                    const int gi = i0 + wa * 16 + c15;
#pragma unroll
                    for (int t = 0; t < 4; t++) {
#pragma unroll
                        for (int r = 0; r < 4; r++) {
                            int gj = j0 + t * 16 + quad * 4 + r;
                            if (gj > gi) sc[t][r] = -1e30f;
                        }
                    }
                }

                float x0 = fmaxf(fmaxf(sc[0][0], sc[0][1]), fmaxf(sc[0][2], sc[0][3]));
                float x1 = fmaxf(fmaxf(sc[1][0], sc[1][1]), fmaxf(sc[1][2], sc[1][3]));
                float x2 = fmaxf(fmaxf(sc[2][0], sc[2][1]), fmaxf(sc[2][2], sc[2][3]));
                float x3 = fmaxf(fmaxf(sc[3][0], sc[3][1]), fmaxf(sc[3][2], sc[3][3]));
                float tm = fmaxf(fmaxf(x0, x1), fmaxf(x2, x3));
                tm = fmaxf(tm, __shfl_xor(tm, 16));
                tm = fmaxf(tm, __shfl_xor(tm, 32));

                if (!__all(tm <= m_st + 64.0f)) {   // defer-max
                    float mnew = fmaxf(m_st, tm);
                    float alpha = __expf((m_st - mnew) * C);
                    l_st *= alpha;
#pragma unroll
                    for (int t = 0; t < 4; t++)
#pragma unroll
                        for (int r = 0; r < 4; r++) Oc[t][r] *= alpha;
                    m_st = mnew;
                }

                const float mC = m_st * C;
                float p[4][4];
#pragma unroll
                for (int t = 0; t < 4; t++)
#pragma unroll
                    for (int r = 0; r < 4; r++)
                        p[t][r] = __expf(__builtin_fmaf(sc[t][r], C, -mC));

                float s0 = (p[0][0] + p[0][1]) + (p[0][2] + p[0][3]);
                float s1 = (p[1][0] + p[1][1]) + (p[1][2] + p[1][3]);
                float s2 = (p[2][0] + p[2][1]) + (p[2][2] + p[2][3]);
                float s3 = (p[3][0] + p[3][1]) + (p[3][2] + p[3][3]);
                l_st += (s0 + s1) + (s2 + s3);

                unsigned int pk[4][2];
#pragma unroll
                for (int t = 0; t < 4; t++)
#pragma unroll
                    for (int hh = 0; hh < 2; hh++)
                        asm("v_cvt_pk_bf16_f32 %0, %1, %2"
                            : "=v"(pk[t][hh]) : "v"(p[t][2 * hh]), "v"(p[t][2 * hh + 1]));

                unsigned int w0[4], w1[4];
#pragma unroll
                for (int e = 0; e < 4; e++) {
                    int sl = c15 + 16 * ((2 * quad + (e >> 1)) & 3);
                    unsigned int a0 = (unsigned int)__shfl((int)pk[0][e & 1], sl);
                    unsigned int b0 = (unsigned int)__shfl((int)pk[1][e & 1], sl);
                    w0[e] = (quad >> 1) ? b0 : a0;
                    unsigned int a1 = (unsigned int)__shfl((int)pk[2][e & 1], sl);
                    unsigned int b1 = (unsigned int)__shfl((int)pk[3][e & 1], sl);
                    w1[e] = (quad >> 1) ? b1 : a1;
                }
                uint4 u0 = make_uint4(w0[0], w0[1], w0[2], w0[3]);
                uint4 u1 = make_uint4(w1[0], w1[1], w1[2], w1[3]);
                bf16x8 ap0 = *reinterpret_cast<bf16x8*>(&u0);
                bf16x8 ap1 = *reinterpret_cast<bf16x8*>(&u1);

                __builtin_amdgcn_s_setprio(1);
#pragma unroll
                for (int t = 0; t < 4; t++) {
                    Oc[t] = __builtin_amdgcn_mfma_f32_16x16x32_bf16(vv0[t], ap0, Oc[t], 0, 0, 0);
                    Oc[t] = __builtin_amdgcn_mfma_f32_16x16x32_bf16(vv1[t], ap1, Oc[t], 0, 0, 0);
                }
                __builtin_amdgcn_s_setprio(0);
            }
        }

        // -------- combine groups (split-K flash merge) --------
        __syncthreads();
        float l_row = l_st;
        l_row += __shfl_xor(l_row, 16);
        l_row += __shfl_xor(l_row, 32);
        const int q = wa * 16 + c15;

        if (grp == 1) {
#pragma unroll
            for (int t = 0; t < 4; t++)
#pragma unroll
                for (int r = 0; r < 4; r++)
                    exch[q * 65 + t * 16 + quad * 4 + r] = Oc[t][r];
            if (quad == 0) ml[q] = make_float2(m_st, l_row);
        }
        __syncthreads();
        if (grp == 0) {
            float2 mlB = ml[q];
            float m = fmaxf(m_st, mlB.x);
            float aA = __expf((m_st - m) * C);
            float aB = __expf((mlB.x - m) * C);
            float inv = 1.0f / (l_row * aA + mlB.y * aB);
#pragma unroll
            for (int t = 0; t < 4; t++) {
#pragma unroll
                for (int hh = 0; hh < 2; hh++) {
                    float o0 = (Oc[t][2 * hh] * aA
                                + exch[q * 65 + t * 16 + quad * 4 + 2 * hh] * aB) * inv;
                    float o1 = (Oc[t][2 * hh + 1] * aA
                                + exch[q * 65 + t * 16 + quad * 4 + 2 * hh + 1] * aB) * inv;
                    unsigned int pko = (unsigned int)f2bf(o0) | ((unsigned int)f2bf(o1) << 16);
                    *reinterpret_cast<unsigned int*>(
                        &ost[q * 72 + t * 16 + quad * 4 + 2 * hh]) = pko;
                }
            }
            {
                int row = lane >> 2;
                int ch = lane & 3;
                int gi = i0 + wa * 16 + row;
                size_t ob = ((size_t)b * SEQ + gi) * 1024 + h * 64 + ch * 16;
                uint4 v0 = *reinterpret_cast<const uint4*>(&ost[(wa * 16 + row) * 72 + ch * 16]);
                uint4 v1 = *reinterpret_cast<const uint4*>(&ost[(wa * 16 + row) * 72 + ch * 16 + 8]);
                *reinterpret_cast<uint4*>(&ab[ob]) = v0;
                *reinterpret_cast<uint4*>(&ab[ob + 8]) = v1;
            }
        }
    }
}

// MFMA NT-GEMM: out[m,n] = sum_i ab[m,i] * Wo[n,i]; bf16 in, fp32 out.
// 64x128 tile, BK=32 (24KB LDS), 512 blocks.
__global__ __launch_bounds__(256) void out_mfma_kernel(
    const unsigned short* __restrict__ A, const unsigned short* __restrict__ Wob,
    float* __restrict__ out)
{
    const int lin = blockIdx.x;
    const int b = lin & 7;
    const int y = lin >> 3;       // 0..63
    const int m0 = y * 64;
    const int n0g = b * 128;

    __shared__ __align__(16) unsigned short As[2][64][32];    // 8 KB
    __shared__ __align__(16) unsigned short Bs[2][128][32];   // 16 KB

    const int tid = threadIdx.x;
    const int w = tid >> 6;
    const int lane = tid & 63;
    const int quad = lane >> 4;
    const int c15 = lane & 15;
    const int qm = w >> 1, qn = w & 1;
    const int srow4 = lane >> 2;
    const int sch4 = lane & 3;

    auto stage = [&](int k0, int buf) {
        {
            const int row = w * 16 + srow4;
            const int ch = sch4 ^ ((row >> 1) & 3);
            gload_lds16(A + (size_t)(m0 + row) * 1024 + k0 + ch * 8,
                        &As[buf][w * 16][0]);
        }
#pragma unroll
        for (int i = 0; i < 2; i++) {
            const int row = i * 64 + w * 16 + srow4;
            const int ch = sch4 ^ ((row >> 1) & 3);
            gload_lds16(Wob + (size_t)(n0g + row) * 1024 + k0 + ch * 8,
                        &Bs[buf][i * 64 + w * 16][0]);
        }
    };

    f32x4 acc[2][4];
#pragma unroll
    for (int mi = 0; mi < 2; mi++)
#pragma unroll
        for (int ni = 0; ni < 4; ni++) acc[mi][ni] = (f32x4){0.f, 0.f, 0.f, 0.f};

    stage(0, 0);
    for (int k0 = 0; k0 < 1024; k0 += 32) {
        const int cb = (k0 >> 5) & 1;
        __syncthreads();
        if (k0 < 992) stage(k0 + 32, cb ^ 1);

        bf16x8 af[2], bfr[4];
#pragma unroll
        for (int mi = 0; mi < 2; mi++)
            af[mi] = lds_read_swz32(As[cb], qm * 32 + mi * 16 + c15, quad);
#pragma unroll
        for (int ni = 0; ni < 4; ni++)
            bfr[ni] = lds_read_swz32(Bs[cb], qn * 64 + ni * 16 + c15, quad);
#pragma unroll
        for (int mi = 0; mi < 2; mi++)
#pragma unroll
            for (int ni = 0; ni < 4; ni++)
                acc[mi][ni] = __builtin_amdgcn_mfma_f32_16x16x32_bf16(af[mi], bfr[ni], acc[mi][ni], 0, 0, 0);
    }

#pragma unroll
    for (int mi = 0; mi < 2; mi++) {
#pragma unroll
        for (int r = 0; r < 4; r++) {
            int m = m0 + qm * 32 + mi * 16 + quad * 4 + r;
#pragma unroll
            for (int ni = 0; ni < 4; ni++) {
                int n = n0g + qn * 64 + ni * 16 + c15;
                out[(size_t)m * 1024 + n] = acc[mi][ni][r];
            }
        }
    }
}

extern "C" void kernel_launch(void* const* d_in, const int* in_sizes, int n_in,
                              void* d_out, int out_size, void* d_ws, size_t ws_size,
                              hipStream_t stream)
{
    const float* x  = (const float*)d_in[0];
    const float* Wq = (const float*)d_in[1];
    const float* Wk = (const float*)d_in[2];
    const float* Wv = (const float*)d_in[3];
    const float* Wo = (const float*)d_in[4];
    float* out = (float*)d_out;

    const size_t QKV_ELEMS = (size_t)BATCH * SEQ * D_MODEL;  // 4194304

    unsigned short* qb = (unsigned short*)d_ws;
    unsigned short* kb = qb + QKV_ELEMS;
    unsigned short* vt = kb + QKV_ELEMS;   // [b][h][d][s]
    unsigned short* ab = vt + QKV_ELEMS;
    unsigned short* w3bf = ab;             // dead during qkv
    unsigned short* xbuf = (unsigned short*)d_out;               // first 8MB of out
    float2* tab = (float2*)((char*)d_out + 8 * 1024 * 1024);     // 512 KB after xbuf

    // Wo-bf16 placement: dedicated region past the 32MB in use, if the
    // workspace allows (fuses the Wo conversion into conv4, one fewer
    // launch); else fall back to the verified 5-launch path (wobf = qb,
    // converted after attn when qb is dead).
    const size_t used = 4 * QKV_ELEMS * sizeof(unsigned short);          // 32 MB
    const size_t wo_bytes = 1048576 * sizeof(unsigned short);            // 2 MB
    if (ws_size >= used + wo_bytes) {
        unsigned short* wobf = qb + 4 * QKV_ELEMS;
        // x + Wq/Wk/Wv + Wo conversion + RoPE table: 2097152 + 65536 threads
        conv4_kernel<<<dim3(8448), 256, 0, stream>>>(x, Wq, Wk, Wv, Wo,
                                                     xbuf, w3bf, wobf, tab);
        qkv_mfma_kernel<<<dim3(768), 256, 0, stream>>>(xbuf, w3bf, tab, qb, kb, vt);
        attn_kernel<<<dim3(32, 16), 512, 0, stream>>>(qb, kb, vt, ab);
        out_mfma_kernel<<<dim3(512), 256, 0, stream>>>(ab, wobf, out);
    } else {
        unsigned short* wobf = qb;         // dead during out
        conv4_kernel<<<dim3(7424), 256, 0, stream>>>(x, Wq, Wk, Wv, Wo,
                                                     xbuf, w3bf, nullptr, tab);
        qkv_mfma_kernel<<<dim3(768), 256, 0, stream>>>(xbuf, w3bf, tab, qb, kb, vt);
        attn_kernel<<<dim3(32, 16), 512, 0, stream>>>(qb, kb, vt, ab);
        conv_kernel<<<dim3(1024), 256, 0, stream>>>(Wo, wobf, 262144);
        out_mfma_kernel<<<dim3(512), 256, 0, stream>>>(ab, wobf, out);
    }
}